// Round 11
// baseline (867.430 us; speedup 1.0000x reference)
//
#include <hip/hip_runtime.h>
#include <hip/hip_bf16.h>
#include <stdint.h>

#define T_TOK 8192
#define D_DIM 1024
#define E_NUM 8
#define H_DIM 4096
#define NPAD 144          // padded wl count, multiple of 8 (wl max = 135)
#define PPX (NPAD / 8)    // panels per XCD chunk = 18

typedef short bf16x8 __attribute__((ext_vector_type(8)));
typedef float f32x4 __attribute__((ext_vector_type(4)));
typedef unsigned short usv8 __attribute__((ext_vector_type(8)));

#define AS1 __attribute__((address_space(1)))
#define AS3 __attribute__((address_space(3)))

__device__ __forceinline__ unsigned short f2b(float f) {
  union { float f; uint32_t u; } v; v.f = f;
  uint32_t r = (v.u + 0x7fffu + ((v.u >> 16) & 1u)) >> 16;
  return (unsigned short)r;
}

__device__ __forceinline__ float gelu_tanh(float x) {
  float u = 0.7978845608028654f * (x + 0.044715f * x * x * x);
  u = fminf(fmaxf(u, -15.f), 15.f);
  float e = __expf(2.f * u);
  float t = (e - 1.f) / (e + 1.f);
  return 0.5f * x * (1.f + t);
}

__device__ __forceinline__ void gload_lds16(const void* g, void* l) {
  __builtin_amdgcn_global_load_lds((const AS1 uint32_t*)g, (AS3 uint32_t*)l, 16, 0, 0);
}

// ---------------- gate + x->bf16 conversion fused ----------------
__global__ __launch_bounds__(256) void moe_gate_conv(const float* __restrict__ x,
                                                     const float* __restrict__ gw,
                                                     const float* __restrict__ gb,
                                                     unsigned short* __restrict__ xb,
                                                     int2* __restrict__ sel,
                                                     float2* __restrict__ wts,
                                                     int* __restrict__ meta) {
  int lane = threadIdx.x & 63;
  int t = blockIdx.x * 4 + (threadIdx.x >> 6);
  const float* xr = x + (size_t)t * D_DIM;
  unsigned short* xo = xb + (size_t)t * D_DIM;
  float acc[8];
#pragma unroll
  for (int e = 0; e < 8; e++) acc[e] = 0.f;
#pragma unroll
  for (int i = 0; i < 4; i++) {
    int d0 = lane * 4 + i * 256;
    float4 xv = *(const float4*)(xr + d0);
    ushort4 o;
    o.x = f2b(xv.x); o.y = f2b(xv.y); o.z = f2b(xv.z); o.w = f2b(xv.w);
    *(ushort4*)(xo + d0) = o;
    const float* gp = gw + (size_t)d0 * 8;
    float xs[4] = {xv.x, xv.y, xv.z, xv.w};
#pragma unroll
    for (int j = 0; j < 4; j++) {
#pragma unroll
      for (int e = 0; e < 8; e++) acc[e] += xs[j] * gp[j * 8 + e];
    }
  }
#pragma unroll
  for (int off = 32; off > 0; off >>= 1) {
#pragma unroll
    for (int e = 0; e < 8; e++) acc[e] += __shfl_xor(acc[e], off);
  }
  if (lane == 0) {
    float lg[8];
#pragma unroll
    for (int e = 0; e < 8; e++) lg[e] = acc[e] + gb[e];
    int e0 = 0; float b0 = lg[0];
#pragma unroll
    for (int e = 1; e < 8; e++) if (lg[e] > b0) { b0 = lg[e]; e0 = e; }
    int e1 = -1; float b1v = -1e30f;
#pragma unroll
    for (int e = 0; e < 8; e++) if (e != e0 && lg[e] > b1v) { b1v = lg[e]; e1 = e; }
    float d = __expf(b1v - b0);
    float w0 = 1.f / (1.f + d), w1 = d / (1.f + d);
    sel[t] = make_int2(e0, e1);
    wts[t] = make_float2(w0, w1);
    atomicAdd(&meta[e0], 1);
    atomicAdd(&meta[e1], 1);
  }
}

// ---------------- fused transpose+convert with coalesced 128B writes ----------------
__global__ __launch_bounds__(256) void moe_transpose2(const float* __restrict__ w1,
                                                      const float* __restrict__ w2,
                                                      unsigned short* __restrict__ w1t,
                                                      unsigned short* __restrict__ w2t) {
  int z = blockIdx.y;
  int e = z & 7;
  const float* in; unsigned short* out; int R, C, cy, ry;
  if (z < 8) { in = w1 + (size_t)e * D_DIM * H_DIM; out = w1t + (size_t)e * D_DIM * H_DIM;
               R = D_DIM; C = H_DIM; cy = blockIdx.x & 63; ry = blockIdx.x >> 6; }
  else       { in = w2 + (size_t)e * H_DIM * D_DIM; out = w2t + (size_t)e * H_DIM * D_DIM;
               R = H_DIM; C = D_DIM; cy = blockIdx.x & 15; ry = blockIdx.x >> 4; }
  int r0 = ry * 64, c0 = cy * 64;
  __shared__ float tile[64][65];
  int t = threadIdx.x;
  int ir = t >> 4, ic = (t & 15) * 4;
#pragma unroll
  for (int p = 0; p < 4; ++p) {
    float4 v = *(const float4*)(in + (size_t)(r0 + ir + p * 16) * C + c0 + ic);
    tile[ir + p * 16][ic] = v.x;     tile[ir + p * 16][ic + 1] = v.y;
    tile[ir + p * 16][ic + 2] = v.z; tile[ir + p * 16][ic + 3] = v.w;
  }
  __syncthreads();
  int orow = t >> 3, oc = (t & 7) * 8;
#pragma unroll
  for (int q = 0; q < 2; ++q) {
    int r = orow + q * 32;
    usv8 o;
#pragma unroll
    for (int j = 0; j < 8; ++j) o[j] = f2b(tile[oc + j][r]);
    *(usv8*)(out + (size_t)(c0 + r) * R + r0 + oc) = o;
  }
}

// meta layout: [0..7] counts, [8..16] offsets(+total), [17] wl_count, [20..27] cursor
__global__ __launch_bounds__(256) void moe_scan(int* meta, int2* wl) {
  int cnt[8];
#pragma unroll
  for (int e = 0; e < 8; e++) cnt[e] = meta[e];
  int t = threadIdx.x;
  if (t < 8) {
    int o = 0;
    for (int e = 0; e < 8; e++) if (e < t) o += cnt[e];
    meta[8 + t] = o;
    meta[20 + t] = o;
  }
  if (t == 8) {
    int o = 0;
#pragma unroll
    for (int e = 0; e < 8; e++) o += cnt[e];
    meta[16] = o;
  }
  int acc = 0, eSel = -1, base = 0;
#pragma unroll
  for (int k = 0; k < 8; k++) {
    int nxt = acc + ((cnt[k] + 127) >> 7);
    if (t >= acc && t < nxt) { eSel = k; base = acc; }
    acc = nxt;
  }
  if (t == 9) meta[17] = acc;
  if (eSel >= 0) wl[t] = make_int2(eSel, (t - base) << 7);
}

__global__ __launch_bounds__(256) void moe_scatter(const int2* __restrict__ sel,
                                                   const float2* __restrict__ wts,
                                                   int* __restrict__ meta,
                                                   int* __restrict__ token_id,
                                                   float* __restrict__ weightv) {
  int t = blockIdx.x * 256 + threadIdx.x;
  if (t >= T_TOK) return;
  int2 s = sel[t];
  float2 w = wts[t];
  int p0 = atomicAdd(&meta[20 + s.x], 1); token_id[p0] = t; weightv[p0] = w.x;
  int p1 = atomicAdd(&meta[20 + s.y], 1); token_id[p1] = t; weightv[p1] = w.y;
}

// ---------------- out init: out[t] = w0*b2[e0] + w1*b2[e1] ----------------
__global__ __launch_bounds__(256) void moe_outinit(const int2* __restrict__ sel,
                                                   const float2* __restrict__ wts,
                                                   const float* __restrict__ b2,
                                                   float* __restrict__ out) {
  int t = blockIdx.x;
  int d = threadIdx.x * 4;
  int2 s = sel[t];
  float2 w = wts[t];
  float4 a = *(const float4*)(b2 + (size_t)s.x * D_DIM + d);
  float4 b = *(const float4*)(b2 + (size_t)s.y * D_DIM + d);
  float4 o;
  o.x = w.x * a.x + w.y * b.x;
  o.y = w.x * a.y + w.y * b.y;
  o.z = w.x * a.z + w.y * b.z;
  o.w = w.x * a.w + w.y * b.w;
  *(float4*)(out + (size_t)t * D_DIM + d) = o;
}

// ---------------- GEMM1 (EXPERIMENT): 3-buffer 2-deep counted-vmcnt pipeline ----------------
// h = gelu(x@w1+b1). Per K-tile: vmcnt(4) -> s_barrier -> stage(T+2) -> ds_read(T) -> MFMA.
__global__ __launch_bounds__(256, 4) void moe_gemm1(const unsigned short* __restrict__ xb,
                                                    const unsigned short* __restrict__ w1t,
                                                    const float* __restrict__ b1,
                                                    const int* __restrict__ meta,
                                                    const int2* __restrict__ wl,
                                                    const int* __restrict__ token_id,
                                                    unsigned short* __restrict__ hbuf) {
  int b = blockIdx.x;
  int c = b & 7, u = b >> 3;
  int n = u & 31, ps = u >> 5;           // NB = 32
  int wi = c * PPX + ps;
  if (wi >= meta[17]) return;
  int e = wl[wi].x, m0 = wl[wi].y;
  int seg = meta[8 + e], ne = meta[9 + e] - seg;
  int n0 = n * 128;
  const unsigned short* wB = w1t + (size_t)e * H_DIM * D_DIM;

  __shared__ unsigned short As[3][4096];
  __shared__ unsigned short Bs[3][4096];

  int tid = threadIdx.x, lane = tid & 63, wv = tid >> 6;
  const unsigned short* aptr[2];
  const unsigned short* bptr[2];
#pragma unroll
  for (int q = 0; q < 2; q++) {
    int chunk = tid + q * 256;
    int row = chunk >> 2;
    int ko = (chunk & 3) * 8;
    int gi = m0 + row; if (gi >= ne) gi = m0;
    int tok = token_id[seg + gi];
    aptr[q] = xb + (size_t)tok * D_DIM + ko;
    bptr[q] = wB + (size_t)(n0 + row) * D_DIM + ko;
  }
  auto stage = [&](int buf, int kt) {
#pragma unroll
    for (int q = 0; q < 2; q++) {
      gload_lds16(aptr[q] + kt * 32, &As[buf][(wv + 4 * q) * 512]);
      gload_lds16(bptr[q] + kt * 32, &Bs[buf][(wv + 4 * q) * 512]);
    }
  };

  f32x4 acc[4][4] = {};
  int wr = wv >> 1, wc = wv & 1;
  int abase = (wr * 64 + (lane & 15)) * 32 + (lane >> 4) * 8;
  int bbase = (wc * 64 + (lane & 15)) * 32 + (lane >> 4) * 8;

  stage(0, 0);
  stage(1, 1);
  const int nk = D_DIM / 32;
  int cur = 0, sb = 2;
  for (int kt = 0; kt < nk; ++kt) {
    if (kt < nk - 1) { asm volatile("s_waitcnt vmcnt(4)" ::: "memory"); }
    else             { asm volatile("s_waitcnt vmcnt(0)" ::: "memory"); }
    __builtin_amdgcn_s_barrier();
    __builtin_amdgcn_sched_barrier(0);
    if (kt + 2 < nk) stage(sb, kt + 2);
    bf16x8 af[4], bfr[4];
#pragma unroll
    for (int m = 0; m < 4; m++) af[m] = *(const bf16x8*)&As[cur][abase + m * 512];
#pragma unroll
    for (int nn = 0; nn < 4; nn++) bfr[nn] = *(const bf16x8*)&Bs[cur][bbase + nn * 512];
#pragma unroll
    for (int m = 0; m < 4; m++)
#pragma unroll
      for (int nn = 0; nn < 4; nn++)
        acc[m][nn] = __builtin_amdgcn_mfma_f32_16x16x32_bf16(af[m], bfr[nn], acc[m][nn], 0, 0, 0);
    __builtin_amdgcn_sched_barrier(0);   // pin reads+MFMAs above next barrier (buf reuse dist 3)
    cur = (cur == 2) ? 0 : cur + 1;
    sb  = (sb  == 2) ? 0 : sb  + 1;
  }

  int rbase = wr * 64 + (lane >> 4) * 4;
  int cbase = n0 + wc * 64 + (lane & 15);
  const float* b1e = b1 + (size_t)e * H_DIM + cbase;
  float bv[4];
#pragma unroll
  for (int nn = 0; nn < 4; nn++) bv[nn] = b1e[nn * 16];
#pragma unroll
  for (int m = 0; m < 4; m++) {
#pragma unroll
    for (int j = 0; j < 4; j++) {
      int gi = m0 + rbase + m * 16 + j;
      if (gi < ne) {
        unsigned short* hrow = hbuf + (size_t)(seg + gi) * H_DIM + cbase;
#pragma unroll
        for (int nn = 0; nn < 4; nn++) {
          float v = acc[m][nn][j] + bv[nn];
          hrow[nn * 16] = f2b(gelu_tanh(v));
        }
      }
    }
  }
}

// ---------------- GEMM2 (CONTROL, r10): BK=32 2-phase + split-K=2, bias via outinit --------
__global__ __launch_bounds__(256, 4) void moe_gemm2(const unsigned short* __restrict__ hbuf,
                                                    const unsigned short* __restrict__ w2t,
                                                    const int* __restrict__ meta,
                                                    const int2* __restrict__ wl,
                                                    const int* __restrict__ token_id,
                                                    const float* __restrict__ weightv,
                                                    float* __restrict__ out) {
  int b = blockIdx.x;
  int c = b & 7, u = b >> 3;
  int n = u & 7, ks = (u >> 3) & 1, ps = u >> 4;   // NB = 8, KS = 2
  int wi = c * PPX + ps;
  if (wi >= meta[17]) return;
  int e = wl[wi].x, m0 = wl[wi].y;
  int seg = meta[8 + e], ne = meta[9 + e] - seg;
  int n0 = n * 128;
  int kbase = ks * 2048;
  const unsigned short* wB = w2t + (size_t)e * D_DIM * H_DIM;

  __shared__ unsigned short As[2][4096];
  __shared__ unsigned short Bs[2][4096];

  int tid = threadIdx.x, lane = tid & 63, wv = tid >> 6;
  const unsigned short* aptr[2];
  const unsigned short* bptr[2];
#pragma unroll
  for (int q = 0; q < 2; q++) {
    int chunk = tid + q * 256;
    int row = chunk >> 2;
    int ko = (chunk & 3) * 8;
    int gi = m0 + row; if (gi >= ne) gi = m0;
    aptr[q] = hbuf + (size_t)(seg + gi) * H_DIM + kbase + ko;
    bptr[q] = wB + (size_t)(n0 + row) * H_DIM + kbase + ko;
  }
  auto stage = [&](int buf, int kt) {
#pragma unroll
    for (int q = 0; q < 2; q++) {
      gload_lds16(aptr[q] + kt * 32, &As[buf][(wv + 4 * q) * 512]);
      gload_lds16(bptr[q] + kt * 32, &Bs[buf][(wv + 4 * q) * 512]);
    }
  };

  f32x4 acc[4][4] = {};
  int wr = wv >> 1, wc = wv & 1;
  int abase = (wr * 64 + (lane & 15)) * 32 + (lane >> 4) * 8;
  int bbase = (wc * 64 + (lane & 15)) * 32 + (lane >> 4) * 8;

  stage(0, 0);
  __syncthreads();
  const int nk = 2048 / 32;   // 64 K-tiles per half
  for (int kt = 0; kt < nk; ++kt) {
    int cur = kt & 1;
    if (kt + 1 < nk) stage(cur ^ 1, kt + 1);
    bf16x8 af[4], bfr[4];
#pragma unroll
    for (int m = 0; m < 4; m++) af[m] = *(const bf16x8*)&As[cur][abase + m * 512];
#pragma unroll
    for (int nn = 0; nn < 4; nn++) bfr[nn] = *(const bf16x8*)&Bs[cur][bbase + nn * 512];
#pragma unroll
    for (int m = 0; m < 4; m++)
#pragma unroll
      for (int nn = 0; nn < 4; nn++)
        acc[m][nn] = __builtin_amdgcn_mfma_f32_16x16x32_bf16(af[m], bfr[nn], acc[m][nn], 0, 0, 0);
    __syncthreads();
  }

  int rbase = wr * 64 + (lane >> 4) * 4;
  int cbase = n0 + wc * 64 + (lane & 15);
#pragma unroll
  for (int m = 0; m < 4; m++) {
#pragma unroll
    for (int j = 0; j < 4; j++) {
      int gi = m0 + rbase + m * 16 + j;
      if (gi < ne) {
        int p = seg + gi;
        int tok = token_id[p];
        float wt = weightv[p];
        float* orow = out + (size_t)tok * D_DIM + cbase;
#pragma unroll
        for (int nn = 0; nn < 4; nn++)
          atomicAdd(&orow[nn * 16], wt * acc[m][nn][j]);
      }
    }
  }
}

extern "C" void kernel_launch(void* const* d_in, const int* in_sizes, int n_in,
                              void* d_out, int out_size, void* d_ws, size_t ws_size,
                              hipStream_t stream) {
  const float* x      = (const float*)d_in[0];
  const float* gate_w = (const float*)d_in[1];
  const float* gate_b = (const float*)d_in[2];
  const float* w1     = (const float*)d_in[3];
  const float* b1     = (const float*)d_in[4];
  const float* w2     = (const float*)d_in[5];
  const float* b2     = (const float*)d_in[6];
  float* out = (float*)d_out;

  uint8_t* ws = (uint8_t*)d_ws;
  unsigned short* hbuf = (unsigned short*)(ws);                 // 128 MiB
  unsigned short* xb   = (unsigned short*)(ws + 134217728ull);  // 16 MiB
  unsigned short* w1t  = (unsigned short*)(ws + 150994944ull);  // 64 MiB
  unsigned short* w2t  = (unsigned short*)(ws + 218103808ull);  // 64 MiB
  int*    token_id = (int*)  (ws + 285212672ull);               // 64 KiB
  float*  weightv  = (float*)(ws + 285278208ull);               // 64 KiB
  float2* wts      = (float2*)(ws + 285343744ull);              // 64 KiB
  int2*   sel      = (int2*) (ws + 285409280ull);               // 64 KiB
  int*    meta     = (int*)  (ws + 285474816ull);               // 512 B
  int2*   wl       = (int2*) (ws + 285475328ull);               // 2 KiB

  hipMemsetAsync(meta, 0, 512, stream);

  moe_gate_conv<<<dim3(T_TOK / 4), 256, 0, stream>>>(x, gate_w, gate_b, xb, sel, wts, meta);
  moe_transpose2<<<dim3(1024, 16), 256, 0, stream>>>(w1, w2, w1t, w2t);
  moe_scan<<<1, 256, 0, stream>>>(meta, wl);
  moe_scatter<<<dim3(T_TOK / 256), 256, 0, stream>>>(sel, wts, meta, token_id, weightv);
  moe_outinit<<<dim3(T_TOK), 256, 0, stream>>>(sel, wts, b2, out);

  moe_gemm1<<<dim3(NPAD * 32), 256, 0, stream>>>(xb, w1t, b1, meta, wl, token_id, hbuf);
  moe_gemm2<<<dim3(NPAD * 16), 256, 0, stream>>>(hbuf, w2t, meta, wl, token_id, weightv, out);
}

// Round 12
// 829.186 us; speedup vs baseline: 1.0461x; 1.0461x over previous
//
#include <hip/hip_runtime.h>
#include <hip/hip_bf16.h>
#include <stdint.h>

#define T_TOK 8192
#define D_DIM 1024
#define E_NUM 8
#define H_DIM 4096
#define NPAD 144          // padded wl count, multiple of 8 (wl max = 135)
#define PPX (NPAD / 8)    // panels per XCD chunk = 18

typedef short bf16x8 __attribute__((ext_vector_type(8)));
typedef float f32x4 __attribute__((ext_vector_type(4)));
typedef unsigned short usv8 __attribute__((ext_vector_type(8)));

#define AS1 __attribute__((address_space(1)))
#define AS3 __attribute__((address_space(3)))

__device__ __forceinline__ unsigned short f2b(float f) {
  union { float f; uint32_t u; } v; v.f = f;
  uint32_t r = (v.u + 0x7fffu + ((v.u >> 16) & 1u)) >> 16;
  return (unsigned short)r;
}

__device__ __forceinline__ float gelu_tanh(float x) {
  float u = 0.7978845608028654f * (x + 0.044715f * x * x * x);
  u = fminf(fmaxf(u, -15.f), 15.f);
  float e = __expf(2.f * u);
  float t = (e - 1.f) / (e + 1.f);
  return 0.5f * x * (1.f + t);
}

__device__ __forceinline__ void gload_lds16(const void* g, void* l) {
  __builtin_amdgcn_global_load_lds((const AS1 uint32_t*)g, (AS3 uint32_t*)l, 16, 0, 0);
}

// ---------------- gate + x->bf16 conversion fused ----------------
__global__ __launch_bounds__(256) void moe_gate_conv(const float* __restrict__ x,
                                                     const float* __restrict__ gw,
                                                     const float* __restrict__ gb,
                                                     unsigned short* __restrict__ xb,
                                                     int2* __restrict__ sel,
                                                     float2* __restrict__ wts,
                                                     int* __restrict__ meta) {
  int lane = threadIdx.x & 63;
  int t = blockIdx.x * 4 + (threadIdx.x >> 6);
  const float* xr = x + (size_t)t * D_DIM;
  unsigned short* xo = xb + (size_t)t * D_DIM;
  float acc[8];
#pragma unroll
  for (int e = 0; e < 8; e++) acc[e] = 0.f;
#pragma unroll
  for (int i = 0; i < 4; i++) {
    int d0 = lane * 4 + i * 256;
    float4 xv = *(const float4*)(xr + d0);
    ushort4 o;
    o.x = f2b(xv.x); o.y = f2b(xv.y); o.z = f2b(xv.z); o.w = f2b(xv.w);
    *(ushort4*)(xo + d0) = o;
    const float* gp = gw + (size_t)d0 * 8;
    float xs[4] = {xv.x, xv.y, xv.z, xv.w};
#pragma unroll
    for (int j = 0; j < 4; j++) {
#pragma unroll
      for (int e = 0; e < 8; e++) acc[e] += xs[j] * gp[j * 8 + e];
    }
  }
#pragma unroll
  for (int off = 32; off > 0; off >>= 1) {
#pragma unroll
    for (int e = 0; e < 8; e++) acc[e] += __shfl_xor(acc[e], off);
  }
  if (lane == 0) {
    float lg[8];
#pragma unroll
    for (int e = 0; e < 8; e++) lg[e] = acc[e] + gb[e];
    int e0 = 0; float b0 = lg[0];
#pragma unroll
    for (int e = 1; e < 8; e++) if (lg[e] > b0) { b0 = lg[e]; e0 = e; }
    int e1 = -1; float b1v = -1e30f;
#pragma unroll
    for (int e = 0; e < 8; e++) if (e != e0 && lg[e] > b1v) { b1v = lg[e]; e1 = e; }
    float d = __expf(b1v - b0);
    float w0 = 1.f / (1.f + d), w1 = d / (1.f + d);
    sel[t] = make_int2(e0, e1);
    wts[t] = make_float2(w0, w1);
    atomicAdd(&meta[e0], 1);
    atomicAdd(&meta[e1], 1);
  }
}

// ---------------- fused transpose+convert with coalesced 128B writes ----------------
__global__ __launch_bounds__(256) void moe_transpose2(const float* __restrict__ w1,
                                                      const float* __restrict__ w2,
                                                      unsigned short* __restrict__ w1t,
                                                      unsigned short* __restrict__ w2t) {
  int z = blockIdx.y;
  int e = z & 7;
  const float* in; unsigned short* out; int R, C, cy, ry;
  if (z < 8) { in = w1 + (size_t)e * D_DIM * H_DIM; out = w1t + (size_t)e * D_DIM * H_DIM;
               R = D_DIM; C = H_DIM; cy = blockIdx.x & 63; ry = blockIdx.x >> 6; }
  else       { in = w2 + (size_t)e * H_DIM * D_DIM; out = w2t + (size_t)e * H_DIM * D_DIM;
               R = H_DIM; C = D_DIM; cy = blockIdx.x & 15; ry = blockIdx.x >> 4; }
  int r0 = ry * 64, c0 = cy * 64;
  __shared__ float tile[64][65];
  int t = threadIdx.x;
  int ir = t >> 4, ic = (t & 15) * 4;
#pragma unroll
  for (int p = 0; p < 4; ++p) {
    float4 v = *(const float4*)(in + (size_t)(r0 + ir + p * 16) * C + c0 + ic);
    tile[ir + p * 16][ic] = v.x;     tile[ir + p * 16][ic + 1] = v.y;
    tile[ir + p * 16][ic + 2] = v.z; tile[ir + p * 16][ic + 3] = v.w;
  }
  __syncthreads();
  int orow = t >> 3, oc = (t & 7) * 8;
#pragma unroll
  for (int q = 0; q < 2; ++q) {
    int r = orow + q * 32;
    usv8 o;
#pragma unroll
    for (int j = 0; j < 8; ++j) o[j] = f2b(tile[oc + j][r]);
    *(usv8*)(out + (size_t)(c0 + r) * R + r0 + oc) = o;
  }
}

// meta layout: [0..7] counts, [8..16] offsets(+total), [17] wl_count, [20..27] cursor
__global__ __launch_bounds__(256) void moe_scan(int* meta, int2* wl) {
  int cnt[8];
#pragma unroll
  for (int e = 0; e < 8; e++) cnt[e] = meta[e];
  int t = threadIdx.x;
  if (t < 8) {
    int o = 0;
    for (int e = 0; e < 8; e++) if (e < t) o += cnt[e];
    meta[8 + t] = o;
    meta[20 + t] = o;
  }
  if (t == 8) {
    int o = 0;
#pragma unroll
    for (int e = 0; e < 8; e++) o += cnt[e];
    meta[16] = o;
  }
  int acc = 0, eSel = -1, base = 0;
#pragma unroll
  for (int k = 0; k < 8; k++) {
    int nxt = acc + ((cnt[k] + 127) >> 7);
    if (t >= acc && t < nxt) { eSel = k; base = acc; }
    acc = nxt;
  }
  if (t == 9) meta[17] = acc;
  if (eSel >= 0) wl[t] = make_int2(eSel, (t - base) << 7);
}

__global__ __launch_bounds__(256) void moe_scatter(const int2* __restrict__ sel,
                                                   const float2* __restrict__ wts,
                                                   int* __restrict__ meta,
                                                   int* __restrict__ token_id,
                                                   float* __restrict__ weightv) {
  int t = blockIdx.x * 256 + threadIdx.x;
  if (t >= T_TOK) return;
  int2 s = sel[t];
  float2 w = wts[t];
  int p0 = atomicAdd(&meta[20 + s.x], 1); token_id[p0] = t; weightv[p0] = w.x;
  int p1 = atomicAdd(&meta[20 + s.y], 1); token_id[p1] = t; weightv[p1] = w.y;
}

// ---------------- out init: out[t] = w0*b2[e0] + w1*b2[e1] ----------------
__global__ __launch_bounds__(256) void moe_outinit(const int2* __restrict__ sel,
                                                   const float2* __restrict__ wts,
                                                   const float* __restrict__ b2,
                                                   float* __restrict__ out) {
  int t = blockIdx.x;
  int d = threadIdx.x * 4;
  int2 s = sel[t];
  float2 w = wts[t];
  float4 a = *(const float4*)(b2 + (size_t)s.x * D_DIM + d);
  float4 b = *(const float4*)(b2 + (size_t)s.y * D_DIM + d);
  float4 o;
  o.x = w.x * a.x + w.y * b.x;
  o.y = w.x * a.y + w.y * b.y;
  o.z = w.x * a.z + w.y * b.z;
  o.w = w.x * a.w + w.y * b.w;
  *(float4*)(out + (size_t)t * D_DIM + d) = o;
}

// Bank-conflict s-XOR swizzle: LDS tile rows of 64B hold 4 16B chunks (s=0..3).
// Physical chunk s_phys = s_log ^ ((row>>1)&3).  Staging: LDS dest linear (DMA),
// source fetches logical chunk for its physical slot.  Fragment reads XOR their
// s by (lane>>1)&3 -- a per-lane constant, folded into the base offset.

// ---------------- GEMM1: h = gelu(x@w1+b1), BK=32 2-phase, swizzled ----------------
__global__ __launch_bounds__(256, 4) void moe_gemm1(const unsigned short* __restrict__ xb,
                                                    const unsigned short* __restrict__ w1t,
                                                    const float* __restrict__ b1,
                                                    const int* __restrict__ meta,
                                                    const int2* __restrict__ wl,
                                                    const int* __restrict__ token_id,
                                                    unsigned short* __restrict__ hbuf) {
  int b = blockIdx.x;
  int c = b & 7, u = b >> 3;
  int n = u & 31, ps = u >> 5;           // NB = 32
  int wi = c * PPX + ps;
  if (wi >= meta[17]) return;
  int e = wl[wi].x, m0 = wl[wi].y;
  int seg = meta[8 + e], ne = meta[9 + e] - seg;
  int n0 = n * 128;
  const unsigned short* wB = w1t + (size_t)e * H_DIM * D_DIM;

  __shared__ unsigned short As[2][4096];
  __shared__ unsigned short Bs[2][4096];

  int tid = threadIdx.x, lane = tid & 63, wv = tid >> 6;
  const unsigned short* aptr[2];
  const unsigned short* bptr[2];
#pragma unroll
  for (int q = 0; q < 2; q++) {
    int chunk = tid + q * 256;
    int row = chunk >> 2;
    int ko = ((chunk & 3) ^ ((chunk >> 3) & 3)) * 8;   // logical s for this physical slot
    int gi = m0 + row; if (gi >= ne) gi = m0;
    int tok = token_id[seg + gi];
    aptr[q] = xb + (size_t)tok * D_DIM + ko;
    bptr[q] = wB + (size_t)(n0 + row) * D_DIM + ko;
  }
  auto stage = [&](int buf, int kt) {
#pragma unroll
    for (int q = 0; q < 2; q++) {
      gload_lds16(aptr[q] + kt * 32, &As[buf][(wv + 4 * q) * 512]);
      gload_lds16(bptr[q] + kt * 32, &Bs[buf][(wv + 4 * q) * 512]);
    }
  };

  f32x4 acc[4][4] = {};
  int wr = wv >> 1, wc = wv & 1;
  int sswz = ((lane >> 4) ^ ((lane >> 1) & 3)) * 8;    // swizzled k-seg, per-lane const
  int abase = (wr * 64 + (lane & 15)) * 32 + sswz;
  int bbase = (wc * 64 + (lane & 15)) * 32 + sswz;

  stage(0, 0);
  __syncthreads();
  const int nk = D_DIM / 32;
  for (int kt = 0; kt < nk; ++kt) {
    int cur = kt & 1;
    if (kt + 1 < nk) stage(cur ^ 1, kt + 1);
    bf16x8 af[4], bfr[4];
#pragma unroll
    for (int m = 0; m < 4; m++) af[m] = *(const bf16x8*)&As[cur][abase + m * 512];
#pragma unroll
    for (int nn = 0; nn < 4; nn++) bfr[nn] = *(const bf16x8*)&Bs[cur][bbase + nn * 512];
#pragma unroll
    for (int m = 0; m < 4; m++)
#pragma unroll
      for (int nn = 0; nn < 4; nn++)
        acc[m][nn] = __builtin_amdgcn_mfma_f32_16x16x32_bf16(af[m], bfr[nn], acc[m][nn], 0, 0, 0);
    __syncthreads();
  }

  int rbase = wr * 64 + (lane >> 4) * 4;
  int cbase = n0 + wc * 64 + (lane & 15);
  const float* b1e = b1 + (size_t)e * H_DIM + cbase;
  float bv[4];
#pragma unroll
  for (int nn = 0; nn < 4; nn++) bv[nn] = b1e[nn * 16];
#pragma unroll
  for (int m = 0; m < 4; m++) {
#pragma unroll
    for (int j = 0; j < 4; j++) {
      int gi = m0 + rbase + m * 16 + j;
      if (gi < ne) {
        unsigned short* hrow = hbuf + (size_t)(seg + gi) * H_DIM + cbase;
#pragma unroll
        for (int nn = 0; nn < 4; nn++) {
          float v = acc[m][nn][j] + bv[nn];
          hrow[nn * 16] = f2b(gelu_tanh(v));
        }
      }
    }
  }
}

// ---------------- GEMM2: BK=32 2-phase + split-K=2, swizzled, bias via outinit ----------
__global__ __launch_bounds__(256, 4) void moe_gemm2(const unsigned short* __restrict__ hbuf,
                                                    const unsigned short* __restrict__ w2t,
                                                    const int* __restrict__ meta,
                                                    const int2* __restrict__ wl,
                                                    const int* __restrict__ token_id,
                                                    const float* __restrict__ weightv,
                                                    float* __restrict__ out) {
  int b = blockIdx.x;
  int c = b & 7, u = b >> 3;
  int n = u & 7, ks = (u >> 3) & 1, ps = u >> 4;   // NB = 8, KS = 2
  int wi = c * PPX + ps;
  if (wi >= meta[17]) return;
  int e = wl[wi].x, m0 = wl[wi].y;
  int seg = meta[8 + e], ne = meta[9 + e] - seg;
  int n0 = n * 128;
  int kbase = ks * 2048;
  const unsigned short* wB = w2t + (size_t)e * D_DIM * H_DIM;

  __shared__ unsigned short As[2][4096];
  __shared__ unsigned short Bs[2][4096];

  int tid = threadIdx.x, lane = tid & 63, wv = tid >> 6;
  const unsigned short* aptr[2];
  const unsigned short* bptr[2];
#pragma unroll
  for (int q = 0; q < 2; q++) {
    int chunk = tid + q * 256;
    int row = chunk >> 2;
    int ko = ((chunk & 3) ^ ((chunk >> 3) & 3)) * 8;
    int gi = m0 + row; if (gi >= ne) gi = m0;
    aptr[q] = hbuf + (size_t)(seg + gi) * H_DIM + kbase + ko;
    bptr[q] = wB + (size_t)(n0 + row) * H_DIM + kbase + ko;
  }
  auto stage = [&](int buf, int kt) {
#pragma unroll
    for (int q = 0; q < 2; q++) {
      gload_lds16(aptr[q] + kt * 32, &As[buf][(wv + 4 * q) * 512]);
      gload_lds16(bptr[q] + kt * 32, &Bs[buf][(wv + 4 * q) * 512]);
    }
  };

  f32x4 acc[4][4] = {};
  int wr = wv >> 1, wc = wv & 1;
  int sswz = ((lane >> 4) ^ ((lane >> 1) & 3)) * 8;
  int abase = (wr * 64 + (lane & 15)) * 32 + sswz;
  int bbase = (wc * 64 + (lane & 15)) * 32 + sswz;

  stage(0, 0);
  __syncthreads();
  const int nk = 2048 / 32;   // 64 K-tiles per half
  for (int kt = 0; kt < nk; ++kt) {
    int cur = kt & 1;
    if (kt + 1 < nk) stage(cur ^ 1, kt + 1);
    bf16x8 af[4], bfr[4];
#pragma unroll
    for (int m = 0; m < 4; m++) af[m] = *(const bf16x8*)&As[cur][abase + m * 512];
#pragma unroll
    for (int nn = 0; nn < 4; nn++) bfr[nn] = *(const bf16x8*)&Bs[cur][bbase + nn * 512];
#pragma unroll
    for (int m = 0; m < 4; m++)
#pragma unroll
      for (int nn = 0; nn < 4; nn++)
        acc[m][nn] = __builtin_amdgcn_mfma_f32_16x16x32_bf16(af[m], bfr[nn], acc[m][nn], 0, 0, 0);
    __syncthreads();
  }

  int rbase = wr * 64 + (lane >> 4) * 4;
  int cbase = n0 + wc * 64 + (lane & 15);
#pragma unroll
  for (int m = 0; m < 4; m++) {
#pragma unroll
    for (int j = 0; j < 4; j++) {
      int gi = m0 + rbase + m * 16 + j;
      if (gi < ne) {
        int p = seg + gi;
        int tok = token_id[p];
        float wt = weightv[p];
        float* orow = out + (size_t)tok * D_DIM + cbase;
#pragma unroll
        for (int nn = 0; nn < 4; nn++)
          atomicAdd(&orow[nn * 16], wt * acc[m][nn][j]);
      }
    }
  }
}

extern "C" void kernel_launch(void* const* d_in, const int* in_sizes, int n_in,
                              void* d_out, int out_size, void* d_ws, size_t ws_size,
                              hipStream_t stream) {
  const float* x      = (const float*)d_in[0];
  const float* gate_w = (const float*)d_in[1];
  const float* gate_b = (const float*)d_in[2];
  const float* w1     = (const float*)d_in[3];
  const float* b1     = (const float*)d_in[4];
  const float* w2     = (const float*)d_in[5];
  const float* b2     = (const float*)d_in[6];
  float* out = (float*)d_out;

  uint8_t* ws = (uint8_t*)d_ws;
  unsigned short* hbuf = (unsigned short*)(ws);                 // 128 MiB
  unsigned short* xb   = (unsigned short*)(ws + 134217728ull);  // 16 MiB
  unsigned short* w1t  = (unsigned short*)(ws + 150994944ull);  // 64 MiB
  unsigned short* w2t  = (unsigned short*)(ws + 218103808ull);  // 64 MiB
  int*    token_id = (int*)  (ws + 285212672ull);               // 64 KiB
  float*  weightv  = (float*)(ws + 285278208ull);               // 64 KiB
  float2* wts      = (float2*)(ws + 285343744ull);              // 64 KiB
  int2*   sel      = (int2*) (ws + 285409280ull);               // 64 KiB
  int*    meta     = (int*)  (ws + 285474816ull);               // 512 B
  int2*   wl       = (int2*) (ws + 285475328ull);               // 2 KiB

  hipMemsetAsync(meta, 0, 512, stream);

  moe_gate_conv<<<dim3(T_TOK / 4), 256, 0, stream>>>(x, gate_w, gate_b, xb, sel, wts, meta);
  moe_transpose2<<<dim3(1024, 16), 256, 0, stream>>>(w1, w2, w1t, w2t);
  moe_scan<<<1, 256, 0, stream>>>(meta, wl);
  moe_scatter<<<dim3(T_TOK / 256), 256, 0, stream>>>(sel, wts, meta, token_id, weightv);
  moe_outinit<<<dim3(T_TOK), 256, 0, stream>>>(sel, wts, b2, out);

  moe_gemm1<<<dim3(NPAD * 32), 256, 0, stream>>>(xb, w1t, b1, meta, wl, token_id, hbuf);
  moe_gemm2<<<dim3(NPAD * 16), 256, 0, stream>>>(hbuf, w2t, meta, wl, token_id, weightv, out);
}

// Round 13
// 795.959 us; speedup vs baseline: 1.0898x; 1.0417x over previous
//
#include <hip/hip_runtime.h>
#include <hip/hip_bf16.h>
#include <stdint.h>

#define T_TOK 8192
#define D_DIM 1024
#define E_NUM 8
#define H_DIM 4096
#define NPAD 144          // padded panel count, multiple of 8 (max panels = 135)
#define PPX (NPAD / 8)    // panels per XCD chunk = 18
#define TRB 16384         // transpose blocks in moe_prep

typedef short bf16x8 __attribute__((ext_vector_type(8)));
typedef float f32x4 __attribute__((ext_vector_type(4)));
typedef unsigned short usv8 __attribute__((ext_vector_type(8)));

#define AS1 __attribute__((address_space(1)))
#define AS3 __attribute__((address_space(3)))

__device__ __forceinline__ unsigned short f2b(float f) {
  union { float f; uint32_t u; } v; v.f = f;
  uint32_t r = (v.u + 0x7fffu + ((v.u >> 16) & 1u)) >> 16;
  return (unsigned short)r;
}

__device__ __forceinline__ float gelu_tanh(float x) {
  float u = 0.7978845608028654f * (x + 0.044715f * x * x * x);
  u = fminf(fmaxf(u, -15.f), 15.f);
  float e = __expf(2.f * u);
  float t = (e - 1.f) / (e + 1.f);
  return 0.5f * x * (1.f + t);
}

__device__ __forceinline__ void gload_lds16(const void* g, void* l) {
  __builtin_amdgcn_global_load_lds((const AS1 uint32_t*)g, (AS3 uint32_t*)l, 16, 0, 0);
}

// ---------------- fused prep: weight transposes + gate + x->bf16 + out bias-init ----------
// blocks [0, TRB): transpose w1/w2 -> bf16 [n][k];  blocks [TRB, TRB+2048): gate 4 tokens.
__global__ __launch_bounds__(256) void moe_prep(const float* __restrict__ x,
                                                const float* __restrict__ gw,
                                                const float* __restrict__ gb,
                                                const float* __restrict__ w1,
                                                const float* __restrict__ w2,
                                                const float* __restrict__ b2,
                                                unsigned short* __restrict__ xb,
                                                unsigned short* __restrict__ w1t,
                                                unsigned short* __restrict__ w2t,
                                                int2* __restrict__ sel,
                                                float2* __restrict__ wts,
                                                int* __restrict__ meta,
                                                float* __restrict__ out) {
  __shared__ float tile[64][65];
  int z = blockIdx.x;
  if (z < TRB) {
    // ------- transpose+convert -------
    const float* in; unsigned short* outp; int R, C, cy, ry;
    int e = (z >> 10) & 7, bx = z & 1023;
    if (z < TRB / 2) { in = w1 + (size_t)e * D_DIM * H_DIM; outp = w1t + (size_t)e * D_DIM * H_DIM;
                       R = D_DIM; C = H_DIM; cy = bx & 63; ry = bx >> 6; }
    else             { in = w2 + (size_t)e * H_DIM * D_DIM; outp = w2t + (size_t)e * H_DIM * D_DIM;
                       R = H_DIM; C = D_DIM; cy = bx & 15; ry = bx >> 4; }
    int r0 = ry * 64, c0 = cy * 64;
    int t = threadIdx.x;
    int ir = t >> 4, ic = (t & 15) * 4;
#pragma unroll
    for (int p = 0; p < 4; ++p) {
      float4 v = *(const float4*)(in + (size_t)(r0 + ir + p * 16) * C + c0 + ic);
      tile[ir + p * 16][ic] = v.x;     tile[ir + p * 16][ic + 1] = v.y;
      tile[ir + p * 16][ic + 2] = v.z; tile[ir + p * 16][ic + 3] = v.w;
    }
    __syncthreads();
    int orow = t >> 3, oc = (t & 7) * 8;
#pragma unroll
    for (int q = 0; q < 2; ++q) {
      int r = orow + q * 32;
      usv8 o;
#pragma unroll
      for (int j = 0; j < 8; ++j) o[j] = f2b(tile[oc + j][r]);
      *(usv8*)(outp + (size_t)(c0 + r) * R + r0 + oc) = o;
    }
    return;
  }
  // ------- gate + convert + out bias-init -------
  int lane = threadIdx.x & 63;
  int t = (z - TRB) * 4 + (threadIdx.x >> 6);
  const float* xr = x + (size_t)t * D_DIM;
  unsigned short* xo = xb + (size_t)t * D_DIM;
  float acc[8];
#pragma unroll
  for (int e = 0; e < 8; e++) acc[e] = 0.f;
#pragma unroll
  for (int i = 0; i < 4; i++) {
    int d0 = lane * 4 + i * 256;
    float4 xv = *(const float4*)(xr + d0);
    ushort4 o;
    o.x = f2b(xv.x); o.y = f2b(xv.y); o.z = f2b(xv.z); o.w = f2b(xv.w);
    *(ushort4*)(xo + d0) = o;
    const float* gp = gw + (size_t)d0 * 8;
    float xs[4] = {xv.x, xv.y, xv.z, xv.w};
#pragma unroll
    for (int j = 0; j < 4; j++) {
#pragma unroll
      for (int e = 0; e < 8; e++) acc[e] += xs[j] * gp[j * 8 + e];
    }
  }
#pragma unroll
  for (int off = 32; off > 0; off >>= 1) {
#pragma unroll
    for (int e = 0; e < 8; e++) acc[e] += __shfl_xor(acc[e], off);
  }
  // butterfly leaves full sums in every lane: all lanes compute top-2 redundantly
  float lg[8];
#pragma unroll
  for (int e = 0; e < 8; e++) lg[e] = acc[e] + gb[e];
  int e0 = 0; float b0v = lg[0];
#pragma unroll
  for (int e = 1; e < 8; e++) if (lg[e] > b0v) { b0v = lg[e]; e0 = e; }
  int e1 = -1; float b1v = -1e30f;
#pragma unroll
  for (int e = 0; e < 8; e++) if (e != e0 && lg[e] > b1v) { b1v = lg[e]; e1 = e; }
  float d = __expf(b1v - b0v);
  float w0 = 1.f / (1.f + d), w1v = d / (1.f + d);
  if (lane == 0) {
    sel[t] = make_int2(e0, e1);
    wts[t] = make_float2(w0, w1v);
    atomicAdd(&meta[e0], 1);
    atomicAdd(&meta[e1], 1);
  }
  // out[t] = w0*b2[e0] + w1*b2[e1]
  const float* ba = b2 + (size_t)e0 * D_DIM;
  const float* bb = b2 + (size_t)e1 * D_DIM;
  float* orow = out + (size_t)t * D_DIM;
#pragma unroll
  for (int k = 0; k < 4; k++) {
    int dd = lane * 4 + k * 256;
    float4 a = *(const float4*)(ba + dd);
    float4 b = *(const float4*)(bb + dd);
    float4 o;
    o.x = w0 * a.x + w1v * b.x;
    o.y = w0 * a.y + w1v * b.y;
    o.z = w0 * a.z + w1v * b.z;
    o.w = w0 * a.w + w1v * b.w;
    *(float4*)(orow + dd) = o;
  }
}

// ---------------- scatter (inline prefix from counts; cursors start at 0) ----------------
__global__ __launch_bounds__(256) void moe_scatter(const int2* __restrict__ sel,
                                                   const float2* __restrict__ wts,
                                                   int* __restrict__ meta,
                                                   int* __restrict__ token_id,
                                                   float* __restrict__ weightv) {
  int t = blockIdx.x * 256 + threadIdx.x;
  if (t >= T_TOK) return;
  int cnt[8];
#pragma unroll
  for (int e = 0; e < 8; e++) cnt[e] = meta[e];
  int2 s = sel[t];
  float2 w = wts[t];
  int o0 = 0, o1 = 0;
#pragma unroll
  for (int e = 0; e < 8; e++) {
    if (e < s.x) o0 += cnt[e];
    if (e < s.y) o1 += cnt[e];
  }
  int p0 = o0 + atomicAdd(&meta[20 + s.x], 1); token_id[p0] = t; weightv[p0] = w.x;
  int p1 = o1 + atomicAdd(&meta[20 + s.y], 1); token_id[p1] = t; weightv[p1] = w.y;
}

// Panel decode from counts: panel slot wi -> (expert e, m0, seg, ne); invalid -> e=-1.
__device__ __forceinline__ bool panel_decode(const int* __restrict__ meta, int wi,
                                             int& e, int& m0, int& seg, int& ne) {
  int acc = 0, pre = 0;
  e = -1;
#pragma unroll
  for (int k = 0; k < 8; k++) {
    int ck = meta[k];
    int nb = (ck + 127) >> 7;
    if (wi >= acc && wi < acc + nb) { e = k; m0 = (wi - acc) << 7; seg = pre; ne = ck; }
    acc += nb; pre += ck;
  }
  return e >= 0;
}

// Bank-conflict s-XOR swizzle (r12, conflicts==0): phys s = log s ^ ((row>>1)&3).

// ---------------- GEMM1: h = gelu(x@w1+b1), BK=32 2-phase, swizzled ----------------
__global__ __launch_bounds__(256, 4) void moe_gemm1(const unsigned short* __restrict__ xb,
                                                    const unsigned short* __restrict__ w1t,
                                                    const float* __restrict__ b1,
                                                    const int* __restrict__ meta,
                                                    const int* __restrict__ token_id,
                                                    unsigned short* __restrict__ hbuf) {
  int b = blockIdx.x;
  int c = b & 7, u = b >> 3;
  int n = u & 31, ps = u >> 5;           // NB = 32
  int e, m0, seg, ne;
  if (!panel_decode(meta, c * PPX + ps, e, m0, seg, ne)) return;
  int n0 = n * 128;
  const unsigned short* wB = w1t + (size_t)e * H_DIM * D_DIM;

  __shared__ unsigned short As[2][4096];
  __shared__ unsigned short Bs[2][4096];

  int tid = threadIdx.x, lane = tid & 63, wv = tid >> 6;
  const unsigned short* aptr[2];
  const unsigned short* bptr[2];
#pragma unroll
  for (int q = 0; q < 2; q++) {
    int chunk = tid + q * 256;
    int row = chunk >> 2;
    int ko = ((chunk & 3) ^ ((chunk >> 3) & 3)) * 8;   // logical s for this physical slot
    int gi = m0 + row; if (gi >= ne) gi = m0;
    int tok = token_id[seg + gi];
    aptr[q] = xb + (size_t)tok * D_DIM + ko;
    bptr[q] = wB + (size_t)(n0 + row) * D_DIM + ko;
  }
  auto stage = [&](int buf, int kt) {
#pragma unroll
    for (int q = 0; q < 2; q++) {
      gload_lds16(aptr[q] + kt * 32, &As[buf][(wv + 4 * q) * 512]);
      gload_lds16(bptr[q] + kt * 32, &Bs[buf][(wv + 4 * q) * 512]);
    }
  };

  f32x4 acc[4][4] = {};
  int wr = wv >> 1, wc = wv & 1;
  int sswz = ((lane >> 4) ^ ((lane >> 1) & 3)) * 8;    // swizzled k-seg, per-lane const
  int abase = (wr * 64 + (lane & 15)) * 32 + sswz;
  int bbase = (wc * 64 + (lane & 15)) * 32 + sswz;

  stage(0, 0);
  __syncthreads();
  const int nk = D_DIM / 32;
  for (int kt = 0; kt < nk; ++kt) {
    int cur = kt & 1;
    if (kt + 1 < nk) stage(cur ^ 1, kt + 1);
    bf16x8 af[4], bfr[4];
#pragma unroll
    for (int m = 0; m < 4; m++) af[m] = *(const bf16x8*)&As[cur][abase + m * 512];
#pragma unroll
    for (int nn = 0; nn < 4; nn++) bfr[nn] = *(const bf16x8*)&Bs[cur][bbase + nn * 512];
#pragma unroll
    for (int m = 0; m < 4; m++)
#pragma unroll
      for (int nn = 0; nn < 4; nn++)
        acc[m][nn] = __builtin_amdgcn_mfma_f32_16x16x32_bf16(af[m], bfr[nn], acc[m][nn], 0, 0, 0);
    __syncthreads();
  }

  int rbase = wr * 64 + (lane >> 4) * 4;
  int cbase = n0 + wc * 64 + (lane & 15);
  const float* b1e = b1 + (size_t)e * H_DIM + cbase;
  float bv[4];
#pragma unroll
  for (int nn = 0; nn < 4; nn++) bv[nn] = b1e[nn * 16];
#pragma unroll
  for (int m = 0; m < 4; m++) {
#pragma unroll
    for (int j = 0; j < 4; j++) {
      int gi = m0 + rbase + m * 16 + j;
      if (gi < ne) {
        unsigned short* hrow = hbuf + (size_t)(seg + gi) * H_DIM + cbase;
#pragma unroll
        for (int nn = 0; nn < 4; nn++) {
          float v = acc[m][nn][j] + bv[nn];
          hrow[nn * 16] = f2b(gelu_tanh(v));
        }
      }
    }
  }
}

// ---------------- GEMM2: BK=32 2-phase + split-K=2, swizzled, bias via prep init ----------
__global__ __launch_bounds__(256, 4) void moe_gemm2(const unsigned short* __restrict__ hbuf,
                                                    const unsigned short* __restrict__ w2t,
                                                    const int* __restrict__ meta,
                                                    const int* __restrict__ token_id,
                                                    const float* __restrict__ weightv,
                                                    float* __restrict__ out) {
  int b = blockIdx.x;
  int c = b & 7, u = b >> 3;
  int n = u & 7, ks = (u >> 3) & 1, ps = u >> 4;   // NB = 8, KS = 2
  int e, m0, seg, ne;
  if (!panel_decode(meta, c * PPX + ps, e, m0, seg, ne)) return;
  int n0 = n * 128;
  int kbase = ks * 2048;
  const unsigned short* wB = w2t + (size_t)e * D_DIM * H_DIM;

  __shared__ unsigned short As[2][4096];
  __shared__ unsigned short Bs[2][4096];

  int tid = threadIdx.x, lane = tid & 63, wv = tid >> 6;
  const unsigned short* aptr[2];
  const unsigned short* bptr[2];
#pragma unroll
  for (int q = 0; q < 2; q++) {
    int chunk = tid + q * 256;
    int row = chunk >> 2;
    int ko = ((chunk & 3) ^ ((chunk >> 3) & 3)) * 8;
    int gi = m0 + row; if (gi >= ne) gi = m0;
    aptr[q] = hbuf + (size_t)(seg + gi) * H_DIM + kbase + ko;
    bptr[q] = wB + (size_t)(n0 + row) * H_DIM + kbase + ko;
  }
  auto stage = [&](int buf, int kt) {
#pragma unroll
    for (int q = 0; q < 2; q++) {
      gload_lds16(aptr[q] + kt * 32, &As[buf][(wv + 4 * q) * 512]);
      gload_lds16(bptr[q] + kt * 32, &Bs[buf][(wv + 4 * q) * 512]);
    }
  };

  f32x4 acc[4][4] = {};
  int wr = wv >> 1, wc = wv & 1;
  int sswz = ((lane >> 4) ^ ((lane >> 1) & 3)) * 8;
  int abase = (wr * 64 + (lane & 15)) * 32 + sswz;
  int bbase = (wc * 64 + (lane & 15)) * 32 + sswz;

  stage(0, 0);
  __syncthreads();
  const int nk = 2048 / 32;   // 64 K-tiles per half
  for (int kt = 0; kt < nk; ++kt) {
    int cur = kt & 1;
    if (kt + 1 < nk) stage(cur ^ 1, kt + 1);
    bf16x8 af[4], bfr[4];
#pragma unroll
    for (int m = 0; m < 4; m++) af[m] = *(const bf16x8*)&As[cur][abase + m * 512];
#pragma unroll
    for (int nn = 0; nn < 4; nn++) bfr[nn] = *(const bf16x8*)&Bs[cur][bbase + nn * 512];
#pragma unroll
    for (int m = 0; m < 4; m++)
#pragma unroll
      for (int nn = 0; nn < 4; nn++)
        acc[m][nn] = __builtin_amdgcn_mfma_f32_16x16x32_bf16(af[m], bfr[nn], acc[m][nn], 0, 0, 0);
    __syncthreads();
  }

  int rbase = wr * 64 + (lane >> 4) * 4;
  int cbase = n0 + wc * 64 + (lane & 15);
#pragma unroll
  for (int m = 0; m < 4; m++) {
#pragma unroll
    for (int j = 0; j < 4; j++) {
      int gi = m0 + rbase + m * 16 + j;
      if (gi < ne) {
        int p = seg + gi;
        int tok = token_id[p];
        float wt = weightv[p];
        float* orow = out + (size_t)tok * D_DIM + cbase;
#pragma unroll
        for (int nn = 0; nn < 4; nn++)
          atomicAdd(&orow[nn * 16], wt * acc[m][nn][j]);
      }
    }
  }
}

extern "C" void kernel_launch(void* const* d_in, const int* in_sizes, int n_in,
                              void* d_out, int out_size, void* d_ws, size_t ws_size,
                              hipStream_t stream) {
  const float* x      = (const float*)d_in[0];
  const float* gate_w = (const float*)d_in[1];
  const float* gate_b = (const float*)d_in[2];
  const float* w1     = (const float*)d_in[3];
  const float* b1     = (const float*)d_in[4];
  const float* w2     = (const float*)d_in[5];
  const float* b2     = (const float*)d_in[6];
  float* out = (float*)d_out;

  uint8_t* ws = (uint8_t*)d_ws;
  unsigned short* hbuf = (unsigned short*)(ws);                 // 128 MiB
  unsigned short* xb   = (unsigned short*)(ws + 134217728ull);  // 16 MiB
  unsigned short* w1t  = (unsigned short*)(ws + 150994944ull);  // 64 MiB
  unsigned short* w2t  = (unsigned short*)(ws + 218103808ull);  // 64 MiB
  int*    token_id = (int*)  (ws + 285212672ull);               // 64 KiB
  float*  weightv  = (float*)(ws + 285278208ull);               // 64 KiB
  float2* wts      = (float2*)(ws + 285343744ull);              // 64 KiB
  int2*   sel      = (int2*) (ws + 285409280ull);               // 64 KiB
  int*    meta     = (int*)  (ws + 285474816ull);               // 512 B

  hipMemsetAsync(meta, 0, 128, stream);

  moe_prep<<<dim3(TRB + T_TOK / 4), 256, 0, stream>>>(
      x, gate_w, gate_b, w1, w2, b2, xb, w1t, w2t, sel, wts, meta, out);
  moe_scatter<<<dim3(T_TOK / 256), 256, 0, stream>>>(sel, wts, meta, token_id, weightv);

  moe_gemm1<<<dim3(NPAD * 32), 256, 0, stream>>>(xb, w1t, b1, meta, token_id, hbuf);
  moe_gemm2<<<dim3(NPAD * 16), 256, 0, stream>>>(hbuf, w2t, meta, token_id, weightv, out);
}